// Round 13
// baseline (76.371 us; speedup 1.0000x reference)
//
#include <hip/hip_runtime.h>
#include <math.h>

#define BATCH 4
#define SEQ   4096
#define EMB   1024
#define HDIM  64
#define NSPLIT 8

typedef __attribute__((ext_vector_type(8))) short bf16x8;
typedef __attribute__((ext_vector_type(4))) float f32x4;

#define MFMA16(a, b, c) __builtin_amdgcn_mfma_f32_16x16x32_bf16(a, b, c, 0, 0, 0)

__device__ __forceinline__ unsigned short f2bf(float f) {
  unsigned int u = __float_as_uint(f);
  u = (u + 0x7FFFu + ((u >> 16) & 1u)) >> 16;   // RNE
  return (unsigned short)u;
}

__device__ __forceinline__ float fexp2(float x) {  // 2^x, hw v_exp_f32
  float r;
  asm("v_exp_f32 %0, %1" : "=v"(r) : "v"(x));
  return r;
}

// ---------------- W pre-transpose: W[1024][64] f32 x3 -> Wt[192][1024] bf16 --
__global__ __launch_bounds__(256) void wt_kernel(
    const float* __restrict__ Wq, const float* __restrict__ Wk,
    const float* __restrict__ Wv, unsigned short* __restrict__ wt) {
  __shared__ float tile[64][65];
  const int bid = blockIdx.x;           // 48 = 3 matrices x 16 k-tiles
  const int m = bid >> 4, kt = bid & 15;
  const float* W = (m == 0) ? Wq : (m == 1) ? Wk : Wv;
  const int tid = threadIdx.x;
  {
    const int r = tid >> 2, c4 = tid & 3;
    const float* src = W + (size_t)(kt * 64 + r) * 64 + c4 * 16;
#pragma unroll
    for (int j = 0; j < 4; ++j) {
      float4 a = *(const float4*)(src + j * 4);
      tile[r][c4 * 16 + j * 4 + 0] = a.x;
      tile[r][c4 * 16 + j * 4 + 1] = a.y;
      tile[r][c4 * 16 + j * 4 + 2] = a.z;
      tile[r][c4 * 16 + j * 4 + 3] = a.w;
    }
  }
  __syncthreads();
  {
    const int col = tid >> 2, kq = tid & 3;
    unsigned short o[16];
#pragma unroll
    for (int j = 0; j < 16; ++j) o[j] = f2bf(tile[kq * 16 + j][col]);
    unsigned short* dst = wt + (size_t)(m * 64 + col) * 1024 + kt * 64 + kq * 16;
    *(bf16x8*)(dst)     = *(bf16x8*)&o[0];
    *(bf16x8*)(dst + 8) = *(bf16x8*)&o[8];
  }
}

// ---------------- QKV projection via MFMA, BK=128 (half the barriers) -------
// 512 blocks (2/CU): 32-row M-tile x 192 cols. 8 K-chunks of 128, bf16 in
// XOR-swizzled LDS (56KB); reg-prefetch of next chunk. Wave w owns 48 cols.
__global__ __launch_bounds__(256) void qkv_mfma_kernel(
    const float* __restrict__ x, const unsigned short* __restrict__ wt,
    unsigned short* __restrict__ qb, unsigned short* __restrict__ kb,
    unsigned short* __restrict__ vt) {
  __shared__ __align__(16) unsigned short xs[32 * 128];   // 8 KB, swizzled
  __shared__ __align__(16) unsigned short ws[192 * 128];  // 48 KB, swizzled
  const int tid  = threadIdx.x;
  const int lane = tid & 63, wid = tid >> 6;
  const int g = lane >> 4, p = lane & 15;
  const size_t row0 = (size_t)blockIdx.x * 32;

  const int sr = tid >> 3, sc = tid & 7;            // x: row, 16-k group
  const float* xp = x + (row0 + sr) * EMB + sc * 16;

  f32x4 acc[2][3];
#pragma unroll
  for (int rt = 0; rt < 2; ++rt)
#pragma unroll
    for (int ct = 0; ct < 3; ++ct) acc[rt][ct] = (f32x4){0.f, 0.f, 0.f, 0.f};

  float4 rx[4];
  bf16x8 rw[12];
#pragma unroll
  for (int j = 0; j < 4; ++j) rx[j] = *(const float4*)(xp + j * 4);
#pragma unroll
  for (int it = 0; it < 12; ++it) {
    int i = tid + it * 256, col = i >> 4, cc = i & 15;
    rw[it] = *(const bf16x8*)(wt + (size_t)col * 1024 + cc * 8);
  }

  for (int kc = 0; kc < 8; ++kc) {
    __syncthreads();                       // previous chunk's reads done
    {
      unsigned short h[16];
#pragma unroll
      for (int j = 0; j < 4; ++j) {
        h[4 * j + 0] = f2bf(rx[j].x); h[4 * j + 1] = f2bf(rx[j].y);
        h[4 * j + 2] = f2bf(rx[j].z); h[4 * j + 3] = f2bf(rx[j].w);
      }
      const int xb = sr * 256 + sc * 32;
      *(bf16x8*)((char*)xs + ((xb)      ^ ((sr & 7) << 4))) = *(bf16x8*)&h[0];
      *(bf16x8*)((char*)xs + ((xb + 16) ^ ((sr & 7) << 4))) = *(bf16x8*)&h[8];
    }
#pragma unroll
    for (int it = 0; it < 12; ++it) {
      int i = tid + it * 256, col = i >> 4, cc = i & 15;
      *(bf16x8*)((char*)ws + ((col * 256 + cc * 16) ^ ((col & 7) << 4))) = rw[it];
    }
    if (kc < 7) {
      const float* xpn = xp + (kc + 1) * 128;
#pragma unroll
      for (int j = 0; j < 4; ++j) rx[j] = *(const float4*)(xpn + j * 4);
#pragma unroll
      for (int it = 0; it < 12; ++it) {
        int i = tid + it * 256, col = i >> 4, cc = i & 15;
        rw[it] = *(const bf16x8*)(wt + (size_t)col * 1024 + (kc + 1) * 128 + cc * 8);
      }
    }
    __syncthreads();
#pragma unroll
    for (int ks = 0; ks < 4; ++ks) {
      bf16x8 af[2];
#pragma unroll
      for (int rt = 0; rt < 2; ++rt) {
        int row = rt * 16 + p;
        af[rt] = *(const bf16x8*)((char*)xs +
                 ((row * 256 + ks * 64 + g * 16) ^ ((row & 7) << 4)));
      }
#pragma unroll
      for (int ct = 0; ct < 3; ++ct) {
        int col = wid * 48 + ct * 16 + p;
        bf16x8 bfr = *(const bf16x8*)((char*)ws +
                     ((col * 256 + ks * 64 + g * 16) ^ ((col & 7) << 4)));
#pragma unroll
        for (int rt = 0; rt < 2; ++rt)
          acc[rt][ct] = MFMA16(af[rt], bfr, acc[rt][ct]);
      }
    }
  }

  const int b     = (int)(row0 >> 12);
  const int tbase = (int)(row0 & 4095);
  unsigned short* vtb = vt + (((size_t)b * 64 + (tbase >> 6)) * 64) * 64 + (tbase & 63);
#pragma unroll
  for (int rt = 0; rt < 2; ++rt)
#pragma unroll
    for (int ct = 0; ct < 3; ++ct) {
      const int c0  = wid * 48 + ct * 16;
      const int mtx = c0 >> 6;
      const int col = (c0 & 63) + p;
#pragma unroll
      for (int r = 0; r < 4; ++r) {
        const int row = rt * 16 + 4 * g + r;
        const float vf = acc[rt][ct][r];
        if (mtx == 0)      qb[(row0 + row) * HDIM + col] = f2bf(vf * 0.0450843714f);
        else if (mtx == 1) kb[(row0 + row) * HDIM + col] = f2bf(vf);
        else               vtb[(size_t)col * 64 + row]   = f2bf(vf);
      }
    }
}

// ---- one 64-key tile from swizzled LDS (round-12 proven body) --------------
__device__ __forceinline__ void tile_body_lds(
    const unsigned short* __restrict__ sKb, const unsigned short* __restrict__ sVb,
    int qrel, bool diag,
    const bf16x8& qf0, const bf16x8& qf1,
    int p, int g, int cA0, int cA1, int srcA, int srcB, bool hi,
    float& m, float& l, f32x4 (&o)[4]) {
  f32x4 sc4[4];
#pragma unroll
  for (int t = 0; t < 4; ++t) {
    const int row = 16 * t + p;
    bf16x8 a0 = *(const bf16x8*)((const char*)sKb + row * 128 + cA0);
    bf16x8 a1 = *(const bf16x8*)((const char*)sKb + row * 128 + cA1);
    f32x4 a = (f32x4){0.f, 0.f, 0.f, 0.f};
    a = MFMA16(a0, qf0, a);
    a = MFMA16(a1, qf1, a);
    sc4[t] = a;
  }
  if (diag) {
#pragma unroll
    for (int t = 0; t < 4; ++t)
#pragma unroll
      for (int r = 0; r < 4; ++r)
        if (16 * t + 4 * g + r > qrel) sc4[t][r] = -1e30f;
  }
  float tm = -3e38f;
#pragma unroll
  for (int t = 0; t < 4; ++t)
#pragma unroll
    for (int r = 0; r < 4; ++r) tm = fmaxf(tm, sc4[t][r]);
  tm = fmaxf(tm, __shfl_xor(tm, 16));
  tm = fmaxf(tm, __shfl_xor(tm, 32));
  if (__any(tm > m + 11.5f)) {               // defer-max (T13)
    float mn = fmaxf(m, tm);
    float c = fexp2(m - mn);
    l *= c;
#pragma unroll
    for (int mi = 0; mi < 4; ++mi) o[mi] *= c;
    m = mn;
  }
  float psum = 0.f;
#pragma unroll
  for (int t = 0; t < 4; ++t)
#pragma unroll
    for (int r = 0; r < 4; ++r) {
      float pv = fexp2(sc4[t][r] - m);
      sc4[t][r] = pv;
      psum += pv;
    }
  l += psum;
  bf16x8 b0, b1;
#pragma unroll
  for (int r = 0; r < 4; ++r) {
    float v0 = __shfl(sc4[0][r], srcA), v1 = __shfl(sc4[1][r], srcA);
    float v2 = __shfl(sc4[0][r], srcB), v3 = __shfl(sc4[1][r], srcB);
    b0[r]     = (short)f2bf(hi ? v1 : v0);
    b0[4 + r] = (short)f2bf(hi ? v3 : v2);
    float u0 = __shfl(sc4[2][r], srcA), u1 = __shfl(sc4[3][r], srcA);
    float u2 = __shfl(sc4[2][r], srcB), u3 = __shfl(sc4[3][r], srcB);
    b1[r]     = (short)f2bf(hi ? u1 : u0);
    b1[4 + r] = (short)f2bf(hi ? u3 : u2);
  }
#pragma unroll
  for (int mi = 0; mi < 4; ++mi) {
    const int rowv = 16 * mi + p;
    bf16x8 va0 = *(const bf16x8*)((const char*)sVb + rowv * 128 + cA0);
    bf16x8 va1 = *(const bf16x8*)((const char*)sVb + rowv * 128 + cA1);
    o[mi] = MFMA16(va0, b0, o[mi]);
    o[mi] = MFMA16(va1, b1, o[mi]);
  }
}

__device__ __forceinline__ void item_map(int g_it, int j, int& kt, bool& isA, bool& diag) {
  if (g_it <= j) { isA = true;  kt = g_it;         diag = (g_it == j); }
  else           { isA = false; kt = g_it - j - 1; diag = (kt == 63 - j); }
}

// ---- flash attention stage 1: LDS-staged K/V shared by 4 waves, NSPLIT=8 ---
// Grid 1024 = 4 blocks/CU (LDS 32KB) -> 16 waves/CU for latency hiding.
// Staging traffic unchanged (each of the 8320 tile-items staged exactly once).
__global__ __launch_bounds__(256) void attn_partial_kernel(
    const unsigned short* __restrict__ qb, const unsigned short* __restrict__ kbm,
    const unsigned short* __restrict__ vt, float* __restrict__ pw) {
  __shared__ __align__(16) unsigned short sK[2][4096];
  __shared__ __align__(16) unsigned short sV[2][4096];
  const int tid = threadIdx.x;
  const int wid = tid >> 6, lane = tid & 63;
  const int g = lane >> 4, p = lane & 15;
  const int bid = blockIdx.x;
  const int sp = bid & 7, j = (bid >> 3) & 31, b = bid >> 8;
  const int jB = 63 - j;
  const int tq0A = j * 64 + 16 * wid;
  const int tq0B = jB * 64 + 16 * wid;

  const char* kbase = (const char*)(kbm + (size_t)b * SEQ * HDIM);
  const char* vbase = (const char*)(vt  + (size_t)b * SEQ * HDIM);

  const unsigned short* qrowA = qb + ((size_t)b * SEQ + tq0A + p) * HDIM;
  const bf16x8 qfA0 = *(const bf16x8*)(qrowA + 8 * g);
  const bf16x8 qfA1 = *(const bf16x8*)(qrowA + 32 + 8 * g);
  const unsigned short* qrowB = qb + ((size_t)b * SEQ + tq0B + p) * HDIM;
  const bf16x8 qfB0 = *(const bf16x8*)(qrowB + 8 * g);
  const bf16x8 qfB1 = *(const bf16x8*)(qrowB + 32 + 8 * g);

  const int slot0 = tid * 16, slot1 = slot0 + 4096;
  const int r0 = slot0 >> 7, koff0 = r0 * 128 + ((slot0 & 127) ^ ((r0 & 7) << 4));
  const int r1 = slot1 >> 7, koff1 = r1 * 128 + ((slot1 & 127) ^ ((r1 & 7) << 4));

  const int swz = (p & 7) << 4;
  const int cA0 = (16 * g) ^ swz, cA1 = (64 + 16 * g) ^ swz;

  const int srcA = (g & 1) * 32 + p;
  const int srcB = srcA + 16;
  const bool hi = (g >> 1) != 0;

  float mA = -1e30f, lA = 0.f, mB = -1e30f, lB = 0.f;
  f32x4 oA[4], oB[4];
#pragma unroll
  for (int mi = 0; mi < 4; ++mi) {
    oA[mi] = (f32x4){0.f, 0.f, 0.f, 0.f};
    oB[mi] = (f32x4){0.f, 0.f, 0.f, 0.f};
  }

  const int cnt = (65 - sp + NSPLIT - 1) / NSPLIT;

  bf16x8 rk0, rk1, rv0, rv1;
  {
    int kt; bool isA, diag;
    item_map(sp, j, kt, isA, diag);
    const char* kk = kbase + (size_t)kt * 8192;
    const char* vv = vbase + (size_t)kt * 8192;
    rk0 = *(const bf16x8*)(kk + koff0); rk1 = *(const bf16x8*)(kk + koff1);
    rv0 = *(const bf16x8*)(vv + koff0); rv1 = *(const bf16x8*)(vv + koff1);
  }

  for (int ii = 0; ii < cnt; ++ii) {
    const int buf = ii & 1;
    __syncthreads();
    *(bf16x8*)((char*)sK[buf] + slot0) = rk0;
    *(bf16x8*)((char*)sK[buf] + slot1) = rk1;
    *(bf16x8*)((char*)sV[buf] + slot0) = rv0;
    *(bf16x8*)((char*)sV[buf] + slot1) = rv1;
    if (ii + 1 < cnt) {                   // T14 issue-early
      int kt; bool isA, diag;
      item_map(sp + (ii + 1) * NSPLIT, j, kt, isA, diag);
      const char* kk = kbase + (size_t)kt * 8192;
      const char* vv = vbase + (size_t)kt * 8192;
      rk0 = *(const bf16x8*)(kk + koff0); rk1 = *(const bf16x8*)(kk + koff1);
      rv0 = *(const bf16x8*)(vv + koff0); rv1 = *(const bf16x8*)(vv + koff1);
    }
    __syncthreads();
    int kt; bool isA, diag;
    item_map(sp + ii * NSPLIT, j, kt, isA, diag);
    if (isA) {
      tile_body_lds(sK[buf], sV[buf], tq0A + p - kt * 64, diag, qfA0, qfA1,
                    p, g, cA0, cA1, srcA, srcB, hi, mA, lA, oA);
    } else {
      tile_body_lds(sK[buf], sV[buf], tq0B + p - kt * 64, diag, qfB0, qfB1,
                    p, g, cA0, cA1, srcA, srcB, hi, mB, lB, oB);
    }
  }

  lA += __shfl_xor(lA, 16); lA += __shfl_xor(lA, 32);
  lB += __shfl_xor(lB, 16); lB += __shfl_xor(lB, 32);

  {
    const int grpA = j * 4 + wid;
    float* pp = pw + ((size_t)(b * 256 + grpA) * NSPLIT + sp) * 1056;
#pragma unroll
    for (int mi = 0; mi < 4; ++mi)
      *(f32x4*)(pp + p * 64 + 16 * mi + 4 * g) = oA[mi];
    if (g == 0) { pp[1024 + p] = mA; pp[1040 + p] = lA; }
  }
  {
    const int grpB = jB * 4 + wid;
    float* pp = pw + ((size_t)(b * 256 + grpB) * NSPLIT + sp) * 1056;
#pragma unroll
    for (int mi = 0; mi < 4; ++mi)
      *(f32x4*)(pp + p * 64 + 16 * mi + 4 * g) = oB[mi];
    if (g == 0) { pp[1024 + p] = mB; pp[1040 + p] = lB; }
  }
}

// ---- stage 2: merge NSPLIT partials per (batch, 16-query group), normalize -
__global__ __launch_bounds__(256) void attn_merge_kernel(
    const float* __restrict__ pw, float* __restrict__ out) {
  const int bid = blockIdx.x;                   // b*256 + grp
  const int b = bid >> 8, grp = bid & 255;
  const int q = threadIdx.x & 15, db = threadIdx.x >> 4;
  const float* pp = pw + (size_t)bid * NSPLIT * 1056;
  float ms[NSPLIT], ls[NSPLIT];
  float mm = -3e38f;
#pragma unroll
  for (int s = 0; s < NSPLIT; ++s) {
    ms[s] = pp[s * 1056 + 1024 + q];
    ls[s] = pp[s * 1056 + 1040 + q];
    mm = fmaxf(mm, ms[s]);
  }
  float L = 0.f, a0 = 0.f, a1 = 0.f, a2 = 0.f, a3 = 0.f;
#pragma unroll
  for (int s = 0; s < NSPLIT; ++s) {
    float sc = fexp2(ms[s] - mm);
    L += ls[s] * sc;
    float4 v = *(const float4*)(pp + s * 1056 + q * 64 + 4 * db);
    a0 += v.x * sc; a1 += v.y * sc; a2 += v.z * sc; a3 += v.w * sc;
  }
  const float inv = 1.f / L;
  float* op = out + ((size_t)b * SEQ + grp * 16 + q) * HDIM + 4 * db;
  op[0] = a0 * inv; op[1] = a1 * inv; op[2] = a2 * inv; op[3] = a3 * inv;
}

extern "C" void kernel_launch(void* const* d_in, const int* in_sizes, int n_in,
                              void* d_out, int out_size, void* d_ws, size_t ws_size,
                              hipStream_t stream) {
  const float* x  = (const float*)d_in[0];
  const float* Wq = (const float*)d_in[1];
  const float* Wk = (const float*)d_in[2];
  const float* Wv = (const float*)d_in[3];
  float* outp = (float*)d_out;

  const size_t rows = (size_t)BATCH * SEQ;        // 16384
  unsigned short* qbf = (unsigned short*)d_ws;
  unsigned short* kbf = qbf + rows * HDIM;
  unsigned short* vtb = kbf + rows * HDIM;
  unsigned short* wt  = vtb + rows * HDIM;        // 192*1024 bf16
  float* pw = (float*)(wt + 192 * 1024);          // 8192 partials x 1056 f32

  wt_kernel<<<dim3(48), dim3(256), 0, stream>>>(Wq, Wk, Wv, wt);
  qkv_mfma_kernel<<<dim3((unsigned)(rows / 32)), dim3(256), 0, stream>>>(x, wt, qbf, kbf, vtb);
  attn_partial_kernel<<<dim3(1024), dim3(256), 0, stream>>>(qbf, kbf, vtb, pw);
  attn_merge_kernel<<<dim3(1024), dim3(256), 0, stream>>>(pw, outp);
}

// Round 14
// 61.592 us; speedup vs baseline: 1.2400x; 1.2400x over previous
//
#include <hip/hip_runtime.h>
#include <math.h>

#define BATCH 4
#define SEQ   4096
#define EMB   1024
#define HDIM  64
#define NSPLIT 4

typedef __attribute__((ext_vector_type(8))) short bf16x8;
typedef __attribute__((ext_vector_type(4))) float f32x4;
typedef __attribute__((ext_vector_type(4))) unsigned int u32x4;

#define MFMA16(a, b, c) __builtin_amdgcn_mfma_f32_16x16x32_bf16(a, b, c, 0, 0, 0)

__device__ __forceinline__ unsigned short f2bf(float f) {
  unsigned int u = __float_as_uint(f);
  u = (u + 0x7FFFu + ((u >> 16) & 1u)) >> 16;   // RNE
  return (unsigned short)u;
}

__device__ __forceinline__ float fexp2(float x) {  // 2^x, hw v_exp_f32
  float r;
  asm("v_exp_f32 %0, %1" : "=v"(r) : "v"(x));
  return r;
}

// ---------------- W pre-transpose: W[1024][64] f32 x3 -> Wt[192][1024] bf16 --
__global__ __launch_bounds__(256) void wt_kernel(
    const float* __restrict__ Wq, const float* __restrict__ Wk,
    const float* __restrict__ Wv, unsigned short* __restrict__ wt) {
  __shared__ float tile[64][65];
  const int bid = blockIdx.x;           // 48 = 3 matrices x 16 k-tiles
  const int m = bid >> 4, kt = bid & 15;
  const float* W = (m == 0) ? Wq : (m == 1) ? Wk : Wv;
  const int tid = threadIdx.x;
  {
    const int r = tid >> 2, c4 = tid & 3;
    const float* src = W + (size_t)(kt * 64 + r) * 64 + c4 * 16;
#pragma unroll
    for (int j = 0; j < 4; ++j) {
      float4 a = *(const float4*)(src + j * 4);
      tile[r][c4 * 16 + j * 4 + 0] = a.x;
      tile[r][c4 * 16 + j * 4 + 1] = a.y;
      tile[r][c4 * 16 + j * 4 + 2] = a.z;
      tile[r][c4 * 16 + j * 4 + 3] = a.w;
    }
  }
  __syncthreads();
  {
    const int col = tid >> 2, kq = tid & 3;
    unsigned short o[16];
#pragma unroll
    for (int j = 0; j < 16; ++j) o[j] = f2bf(tile[kq * 16 + j][col]);
    unsigned short* dst = wt + (size_t)(m * 64 + col) * 1024 + kt * 64 + kq * 16;
    *(bf16x8*)(dst)     = *(bf16x8*)&o[0];
    *(bf16x8*)(dst + 8) = *(bf16x8*)&o[8];
  }
}

// ---------------- QKV projection via MFMA (round-12 proven version) ---------
__global__ __launch_bounds__(256) void qkv_mfma_kernel(
    const float* __restrict__ x, const unsigned short* __restrict__ wt,
    unsigned short* __restrict__ qb, unsigned short* __restrict__ kb,
    unsigned short* __restrict__ vt) {
  __shared__ __align__(16) unsigned short xs[32 * 64];
  __shared__ __align__(16) unsigned short ws[192 * 64];
  const int tid  = threadIdx.x;
  const int lane = tid & 63, wid = tid >> 6;
  const int g = lane >> 4, p = lane & 15;
  const size_t row0 = (size_t)blockIdx.x * 32;

  const int sr = tid >> 3, sc = tid & 7;
  const float* xp = x + (row0 + sr) * EMB + sc * 8;

  f32x4 acc[2][3];
#pragma unroll
  for (int rt = 0; rt < 2; ++rt)
#pragma unroll
    for (int ct = 0; ct < 3; ++ct) acc[rt][ct] = (f32x4){0.f, 0.f, 0.f, 0.f};

  float4 rx[2];
  bf16x8 rw[6];
#pragma unroll
  for (int j = 0; j < 2; ++j) rx[j] = *(const float4*)(xp + j * 4);
#pragma unroll
  for (int it = 0; it < 6; ++it) {
    int i = tid + it * 256, col = i >> 3, cc = i & 7;
    rw[it] = *(const bf16x8*)(wt + (size_t)col * 1024 + cc * 8);
  }

  for (int kc = 0; kc < 16; ++kc) {
    __syncthreads();
#pragma unroll
    for (int j = 0; j < 2; ++j) {
      ushort4 h;
      h.x = f2bf(rx[j].x); h.y = f2bf(rx[j].y);
      h.z = f2bf(rx[j].z); h.w = f2bf(rx[j].w);
      *(ushort4*)((char*)xs + ((sr * 128 + sc * 16 + j * 8) ^ ((sr & 7) << 4))) = h;
    }
#pragma unroll
    for (int it = 0; it < 6; ++it) {
      int i = tid + it * 256, col = i >> 3, cc = i & 7;
      *(bf16x8*)((char*)ws + ((col * 128 + cc * 16) ^ ((col & 7) << 4))) = rw[it];
    }
    if (kc < 15) {
      const float* xpn = xp + (kc + 1) * 64;
#pragma unroll
      for (int j = 0; j < 2; ++j) rx[j] = *(const float4*)(xpn + j * 4);
#pragma unroll
      for (int it = 0; it < 6; ++it) {
        int i = tid + it * 256, col = i >> 3, cc = i & 7;
        rw[it] = *(const bf16x8*)(wt + (size_t)col * 1024 + (kc + 1) * 64 + cc * 8);
      }
    }
    __syncthreads();
#pragma unroll
    for (int ks = 0; ks < 2; ++ks) {
      bf16x8 af[2];
#pragma unroll
      for (int rt = 0; rt < 2; ++rt) {
        int row = rt * 16 + p;
        af[rt] = *(const bf16x8*)((char*)xs +
                 ((row * 128 + ks * 64 + g * 16) ^ ((row & 7) << 4)));
      }
#pragma unroll
      for (int ct = 0; ct < 3; ++ct) {
        int col = wid * 48 + ct * 16 + p;
        bf16x8 bfr = *(const bf16x8*)((char*)ws +
                     ((col * 128 + ks * 64 + g * 16) ^ ((col & 7) << 4)));
#pragma unroll
        for (int rt = 0; rt < 2; ++rt)
          acc[rt][ct] = MFMA16(af[rt], bfr, acc[rt][ct]);
      }
    }
  }

  const int b     = (int)(row0 >> 12);
  const int tbase = (int)(row0 & 4095);
  unsigned short* vtb = vt + (((size_t)b * 64 + (tbase >> 6)) * 64) * 64 + (tbase & 63);
#pragma unroll
  for (int rt = 0; rt < 2; ++rt)
#pragma unroll
    for (int ct = 0; ct < 3; ++ct) {
      const int c0  = wid * 48 + ct * 16;
      const int mtx = c0 >> 6;
      const int col = (c0 & 63) + p;
#pragma unroll
      for (int r = 0; r < 4; ++r) {
        const int row = rt * 16 + 4 * g + r;
        const float vf = acc[rt][ct][r];
        if (mtx == 0)      qb[(row0 + row) * HDIM + col] = f2bf(vf * 0.0450843714f);
        else if (mtx == 1) kb[(row0 + row) * HDIM + col] = f2bf(vf);
        else               vtb[(size_t)col * 64 + row]   = f2bf(vf);
      }
    }
}

// ---- one 64-key tile from swizzled LDS; cvt_pk + word-shuffle transpose ----
__device__ __forceinline__ void tile_body_lds(
    const unsigned short* __restrict__ sKb, const unsigned short* __restrict__ sVb,
    int qrel, bool diag,
    const bf16x8& qf0, const bf16x8& qf1,
    int p, int g, int cA0, int cA1, int srcA, int srcB, bool hi,
    float& m, float& l, f32x4 (&o)[4]) {
  f32x4 sc4[4];
#pragma unroll
  for (int t = 0; t < 4; ++t) {
    const int row = 16 * t + p;
    bf16x8 a0 = *(const bf16x8*)((const char*)sKb + row * 128 + cA0);
    bf16x8 a1 = *(const bf16x8*)((const char*)sKb + row * 128 + cA1);
    f32x4 a = (f32x4){0.f, 0.f, 0.f, 0.f};
    a = MFMA16(a0, qf0, a);
    a = MFMA16(a1, qf1, a);
    sc4[t] = a;
  }
  if (diag) {
#pragma unroll
    for (int t = 0; t < 4; ++t)
#pragma unroll
      for (int r = 0; r < 4; ++r)
        if (16 * t + 4 * g + r > qrel) sc4[t][r] = -1e30f;
  }
  float tm = -3e38f;
#pragma unroll
  for (int t = 0; t < 4; ++t)
#pragma unroll
    for (int r = 0; r < 4; ++r) tm = fmaxf(tm, sc4[t][r]);
  tm = fmaxf(tm, __shfl_xor(tm, 16));
  tm = fmaxf(tm, __shfl_xor(tm, 32));
  if (__any(tm > m + 11.5f)) {               // defer-max (T13)
    float mn = fmaxf(m, tm);
    float c = fexp2(m - mn);
    l *= c;
#pragma unroll
    for (int mi = 0; mi < 4; ++mi) o[mi] *= c;
    m = mn;
  }
  float psum = 0.f;
#pragma unroll
  for (int t = 0; t < 4; ++t)
#pragma unroll
    for (int r = 0; r < 4; ++r) {
      float pv = fexp2(sc4[t][r] - m);
      sc4[t][r] = pv;
      psum += pv;
    }
  l += psum;
  // ---- P^T -> B-frags: 8 cvt_pk + 16 word shuffles + 8 selects -------------
  // pk[t][0] = {bf16(P[t][1]), bf16(P[t][0])}, pk[t][1] = {P[t][3], P[t][2]}
  unsigned int pk[4][2];
#pragma unroll
  for (int t = 0; t < 4; ++t) {
    asm("v_cvt_pk_bf16_f32 %0, %1, %2"
        : "=v"(pk[t][0]) : "v"(sc4[t][0]), "v"(sc4[t][1]));
    asm("v_cvt_pk_bf16_f32 %0, %1, %2"
        : "=v"(pk[t][1]) : "v"(sc4[t][2]), "v"(sc4[t][3]));
  }
  u32x4 wb0, wb1;
#pragma unroll
  for (int h2 = 0; h2 < 2; ++h2) {
    const int src = h2 ? srcB : srcA;
    unsigned c0 = (unsigned)__shfl((int)pk[0][0], src);
    unsigned c1 = (unsigned)__shfl((int)pk[1][0], src);
    wb0[2 * h2 + 0] = hi ? c1 : c0;
    unsigned d0 = (unsigned)__shfl((int)pk[0][1], src);
    unsigned d1 = (unsigned)__shfl((int)pk[1][1], src);
    wb0[2 * h2 + 1] = hi ? d1 : d0;
    unsigned e0 = (unsigned)__shfl((int)pk[2][0], src);
    unsigned e1 = (unsigned)__shfl((int)pk[3][0], src);
    wb1[2 * h2 + 0] = hi ? e1 : e0;
    unsigned f0 = (unsigned)__shfl((int)pk[2][1], src);
    unsigned f1 = (unsigned)__shfl((int)pk[3][1], src);
    wb1[2 * h2 + 1] = hi ? f1 : f0;
  }
  bf16x8 b0 = __builtin_bit_cast(bf16x8, wb0);
  bf16x8 b1 = __builtin_bit_cast(bf16x8, wb1);
#pragma unroll
  for (int mi = 0; mi < 4; ++mi) {
    const int rowv = 16 * mi + p;
    bf16x8 va0 = *(const bf16x8*)((const char*)sVb + rowv * 128 + cA0);
    bf16x8 va1 = *(const bf16x8*)((const char*)sVb + rowv * 128 + cA1);
    o[mi] = MFMA16(va0, b0, o[mi]);
    o[mi] = MFMA16(va1, b1, o[mi]);
  }
}

__device__ __forceinline__ void item_map(int g_it, int j, int& kt, bool& isA, bool& diag) {
  if (g_it <= j) { isA = true;  kt = g_it;         diag = (g_it == j); }
  else           { isA = false; kt = g_it - j - 1; diag = (kt == 63 - j); }
}

// ---- flash attention stage 1: LDS-staged K/V shared by 4 waves, NSPLIT=4 ---
__global__ __launch_bounds__(256) void attn_partial_kernel(
    const unsigned short* __restrict__ qb, const unsigned short* __restrict__ kbm,
    const unsigned short* __restrict__ vt, float* __restrict__ pw) {
  __shared__ __align__(16) unsigned short sK[2][4096];
  __shared__ __align__(16) unsigned short sV[2][4096];
  const int tid = threadIdx.x;
  const int wid = tid >> 6, lane = tid & 63;
  const int g = lane >> 4, p = lane & 15;
  const int bid = blockIdx.x;
  const int sp = bid & 3, j = (bid >> 2) & 31, b = bid >> 7;
  const int jB = 63 - j;
  const int tq0A = j * 64 + 16 * wid;
  const int tq0B = jB * 64 + 16 * wid;

  const char* kbase = (const char*)(kbm + (size_t)b * SEQ * HDIM);
  const char* vbase = (const char*)(vt  + (size_t)b * SEQ * HDIM);

  const unsigned short* qrowA = qb + ((size_t)b * SEQ + tq0A + p) * HDIM;
  const bf16x8 qfA0 = *(const bf16x8*)(qrowA + 8 * g);
  const bf16x8 qfA1 = *(const bf16x8*)(qrowA + 32 + 8 * g);
  const unsigned short* qrowB = qb + ((size_t)b * SEQ + tq0B + p) * HDIM;
  const bf16x8 qfB0 = *(const bf16x8*)(qrowB + 8 * g);
  const bf16x8 qfB1 = *(const bf16x8*)(qrowB + 32 + 8 * g);

  const int slot0 = tid * 16, slot1 = slot0 + 4096;
  const int r0 = slot0 >> 7, koff0 = r0 * 128 + ((slot0 & 127) ^ ((r0 & 7) << 4));
  const int r1 = slot1 >> 7, koff1 = r1 * 128 + ((slot1 & 127) ^ ((r1 & 7) << 4));

  const int swz = (p & 7) << 4;
  const int cA0 = (16 * g) ^ swz, cA1 = (64 + 16 * g) ^ swz;

  const int srcA = (g & 1) * 32 + p;
  const int srcB = srcA + 16;
  const bool hi = (g >> 1) != 0;

  float mA = -1e30f, lA = 0.f, mB = -1e30f, lB = 0.f;
  f32x4 oA[4], oB[4];
#pragma unroll
  for (int mi = 0; mi < 4; ++mi) {
    oA[mi] = (f32x4){0.f, 0.f, 0.f, 0.f};
    oB[mi] = (f32x4){0.f, 0.f, 0.f, 0.f};
  }

  const int cnt = (65 - sp + NSPLIT - 1) / NSPLIT;   // 16 or 17

  bf16x8 rk0, rk1, rv0, rv1;
  {
    int kt; bool isA, diag;
    item_map(sp, j, kt, isA, diag);
    const char* kk = kbase + (size_t)kt * 8192;
    const char* vv = vbase + (size_t)kt * 8192;
    rk0 = *(const bf16x8*)(kk + koff0); rk1 = *(const bf16x8*)(kk + koff1);
    rv0 = *(const bf16x8*)(vv + koff0); rv1 = *(const bf16x8*)(vv + koff1);
  }

  for (int ii = 0; ii < cnt; ++ii) {
    const int buf = ii & 1;
    __syncthreads();
    *(bf16x8*)((char*)sK[buf] + slot0) = rk0;
    *(bf16x8*)((char*)sK[buf] + slot1) = rk1;
    *(bf16x8*)((char*)sV[buf] + slot0) = rv0;
    *(bf16x8*)((char*)sV[buf] + slot1) = rv1;
    if (ii + 1 < cnt) {                   // T14 issue-early
      int kt; bool isA, diag;
      item_map(sp + (ii + 1) * NSPLIT, j, kt, isA, diag);
      const char* kk = kbase + (size_t)kt * 8192;
      const char* vv = vbase + (size_t)kt * 8192;
      rk0 = *(const bf16x8*)(kk + koff0); rk1 = *(const bf16x8*)(kk + koff1);
      rv0 = *(const bf16x8*)(vv + koff0); rv1 = *(const bf16x8*)(vv + koff1);
    }
    __syncthreads();
    int kt; bool isA, diag;
    item_map(sp + ii * NSPLIT, j, kt, isA, diag);
    if (isA) {
      tile_body_lds(sK[buf], sV[buf], tq0A + p - kt * 64, diag, qfA0, qfA1,
                    p, g, cA0, cA1, srcA, srcB, hi, mA, lA, oA);
    } else {
      tile_body_lds(sK[buf], sV[buf], tq0B + p - kt * 64, diag, qfB0, qfB1,
                    p, g, cA0, cA1, srcA, srcB, hi, mB, lB, oB);
    }
  }

  lA += __shfl_xor(lA, 16); lA += __shfl_xor(lA, 32);
  lB += __shfl_xor(lB, 16); lB += __shfl_xor(lB, 32);

  {
    const int grpA = j * 4 + wid;
    float* pp = pw + ((size_t)(b * 256 + grpA) * NSPLIT + sp) * 1056;
#pragma unroll
    for (int mi = 0; mi < 4; ++mi)
      *(f32x4*)(pp + p * 64 + 16 * mi + 4 * g) = oA[mi];
    if (g == 0) { pp[1024 + p] = mA; pp[1040 + p] = lA; }
  }
  {
    const int grpB = jB * 4 + wid;
    float* pp = pw + ((size_t)(b * 256 + grpB) * NSPLIT + sp) * 1056;
#pragma unroll
    for (int mi = 0; mi < 4; ++mi)
      *(f32x4*)(pp + p * 64 + 16 * mi + 4 * g) = oB[mi];
    if (g == 0) { pp[1024 + p] = mB; pp[1040 + p] = lB; }
  }
}

// ---- stage 2: merge NSPLIT partials per (batch, 16-query group), normalize -
__global__ __launch_bounds__(256) void attn_merge_kernel(
    const float* __restrict__ pw, float* __restrict__ out) {
  const int bid = blockIdx.x;                   // b*256 + grp
  const int b = bid >> 8, grp = bid & 255;
  const int q = threadIdx.x & 15, db = threadIdx.x >> 4;
  const float* pp = pw + (size_t)bid * NSPLIT * 1056;
  float ms[NSPLIT], ls[NSPLIT];
  float mm = -3e38f;
#pragma unroll
  for (int s = 0; s < NSPLIT; ++s) {
    ms[s] = pp[s * 1056 + 1024 + q];
    ls[s] = pp[s * 1056 + 1040 + q];
    mm = fmaxf(mm, ms[s]);
  }
  float L = 0.f, a0 = 0.f, a1 = 0.f, a2 = 0.f, a3 = 0.f;
#pragma unroll
  for (int s = 0; s < NSPLIT; ++s) {
    float sc = fexp2(ms[s] - mm);
    L += ls[s] * sc;
    float4 v = *(const float4*)(pp + s * 1056 + q * 64 + 4 * db);
    a0 += v.x * sc; a1 += v.y * sc; a2 += v.z * sc; a3 += v.w * sc;
  }
  const float inv = 1.f / L;
  float* op = out + ((size_t)b * SEQ + grp * 16 + q) * HDIM + 4 * db;
  op[0] = a0 * inv; op[1] = a1 * inv; op[2] = a2 * inv; op[3] = a3 * inv;
}

extern "C" void kernel_launch(void* const* d_in, const int* in_sizes, int n_in,
                              void* d_out, int out_size, void* d_ws, size_t ws_size,
                              hipStream_t stream) {
  const float* x  = (const float*)d_in[0];
  const float* Wq = (const float*)d_in[1];
  const float* Wk = (const float*)d_in[2];
  const float* Wv = (const float*)d_in[3];
  float* outp = (float*)d_out;

  const size_t rows = (size_t)BATCH * SEQ;        // 16384
  unsigned short* qbf = (unsigned short*)d_ws;
  unsigned short* kbf = qbf + rows * HDIM;
  unsigned short* vtb = kbf + rows * HDIM;
  unsigned short* wt  = vtb + rows * HDIM;        // 192*1024 bf16
  float* pw = (float*)(wt + 192 * 1024);          // 4096 partials x 1056 f32

  wt_kernel<<<dim3(48), dim3(256), 0, stream>>>(Wq, Wk, Wv, wt);
  qkv_mfma_kernel<<<dim3((unsigned)(rows / 32)), dim3(256), 0, stream>>>(x, wt, qbf, kbf, vtb);
  attn_partial_kernel<<<dim3(512), dim3(256), 0, stream>>>(qbf, kbf, vtb, pw);
  attn_merge_kernel<<<dim3(1024), dim3(256), 0, stream>>>(pw, outp);
}